// Round 10
// baseline (2507.769 us; speedup 1.0000x reference)
//
#include <hip/hip_runtime.h>
#include <hip/hip_bf16.h>

// GRU-GAN generator, MI355X. Round 10 — ONE barrier/step via redundant latent.
// B=512, H=64, S=2048, F=32. 32 blocks x 512 threads (8 waves, 2/SIMD).
// Block = 16 batch rows (M=16 MFMA tile, transposed D[j][m] layout).
// R6-R9 plateau (~1755 cy/step) was the 2-barrier serial structure: two
// cross-wave LDS handoffs (h then x) per step, all waves gated on the slowest
// chain twice. R10 removes the x handoff: EVERY wave computes the full latent
// redundantly (16 extra MFMAs — MFMA pipe was ~15% busy), so x(t+1) is
// in-register in its consumer. The D->A layout fix for x is wave-local (own
// LDS scratch write+readback; per-wave DS ordering, no barrier). Out-proj +
// y store fold into waves 0/1 in the same window (no ping-pong, no epilogue).
// Step = 1 window, 1 barrier:
//   read Hs(h(t+1), both dirs) -> latent 4 tiles (2x2-chain MFMA) -> lk ->
//   xscr/x2scr -> readback A-frags -> [w0/1: out-proj + y(t) store] ->
//   gi/gh 2-chains -> merged-rcp GRU -> h(t+2) -> Hs -> barrier.
// ~230 VGPR of resident weight fragments (12 gate + 16 latent + 2 out) —
// 2 waves/SIMD budget (256). VGPR_Count is the spill falsifier.

#define NBATCH 512
#define NH 64
#define NS 2048
#define NF 32
#define MROW 16
#define LDH 72    // padded LDS row stride (shorts): 144 B

typedef short s16x8 __attribute__((ext_vector_type(8)));
typedef float f32x4 __attribute__((ext_vector_type(4)));

#define MFMA(a, b, c) __builtin_amdgcn_mfma_f32_16x16x32_bf16((a), (b), (c), 0, 0, 0)

#define NLOG2E  (-1.4426950408889634f)   // -log2(e)
#define N2LOG2E (-2.8853900817779268f)   // -2*log2(e)

__device__ __forceinline__ short f2bf(float f) {
    return (short)((__float_as_uint(f) + 0x8000u) >> 16);
}

__device__ __forceinline__ f32x4 v_exp2(f32x4 a) {
    f32x4 r;
#pragma unroll
    for (int i = 0; i < 4; ++i) r[i] = __builtin_amdgcn_exp2f(a[i]);
    return r;
}

__device__ __forceinline__ f32x4 v_rcp(f32x4 a) {
    f32x4 r;
#pragma unroll
    for (int i = 0; i < 4; ++i) r[i] = __builtin_amdgcn_rcpf(a[i]);
    return r;
}

__device__ __forceinline__ f32x4 v_lk(f32x4 a) {
    f32x4 b = a * 0.01f;
    f32x4 r;
#pragma unroll
    for (int i = 0; i < 4; ++i) r[i] = fmaxf(a[i], b[i]);
    return r;
}

__device__ __forceinline__ f32x4 v_sigm(f32x4 a) {
    return v_rcp(v_exp2(a * NLOG2E) + 1.0f);
}

__device__ __forceinline__ int2 pk4bf(f32x4 v) {
    union { __hip_bfloat162 b; int i; } lo, hi;
    float2 a; a.x = v[0]; a.y = v[1];
    float2 b; b.x = v[2]; b.y = v[3];
    lo.b = __float22bfloat162_rn(a);
    hi.b = __float22bfloat162_rn(b);
    int2 r; r.x = lo.i; r.y = hi.i;
    return r;
}

// exact merged-rcp GRU update (R8): one rcp, algebraically = sigmoid/tanh form
__device__ __forceinline__ f32x4 gru_up(f32x4 aR, f32x4 aZ, f32x4 aN1,
                                        f32x4 aN2, f32x4 h) {
    f32x4 eR = v_exp2(aR * NLOG2E);
    f32x4 rr = v_rcp(eR + 1.0f);
    f32x4 u  = aN1 + rr * aN2;
    f32x4 eU = v_exp2(u * N2LOG2E);
    f32x4 eZ = v_exp2(aZ * NLOG2E);
    f32x4 numer = (eZ + h) + eU * (h - eZ);
    f32x4 denom = (eU + 1.0f) * (eZ + 1.0f);
    return numer * v_rcp(denom);
}

// Weight fragment: lane holds 8 consecutive elements of row `row` of
// row-major W (fp32 -> bf16). Serves as A-operand (m = lane&15 = row sel).
__device__ __forceinline__ s16x8 bfragW(const float* __restrict__ W, int ldk,
                                        int row, int kf, int quad) {
    const float* p = W + (size_t)row * ldk + kf * 32 + quad * 8;
    s16x8 r;
#pragma unroll
    for (int i = 0; i < 8; ++i) r[i] = f2bf(p[i]);
    return r;
}

__device__ __forceinline__ f32x4 bias4(const float* __restrict__ p) {
    const float4 v = *(const float4*)p;
    f32x4 r = {v.x, v.y, v.z, v.w};
    return r;
}

__global__ __launch_bounds__(512)
__attribute__((amdgpu_waves_per_eu(2, 2)))
void grugan_kernel(const float* __restrict__ noise,
                   const float* __restrict__ Wihf, const float* __restrict__ Whhf,
                   const float* __restrict__ bihf, const float* __restrict__ bhhf,
                   const float* __restrict__ Wihb, const float* __restrict__ Whhb,
                   const float* __restrict__ bihb, const float* __restrict__ bhhb,
                   const float* __restrict__ Wlat, const float* __restrict__ blat,
                   const float* __restrict__ Wout, const float* __restrict__ bout,
                   float* __restrict__ out)
{
    __shared__ __align__(16) short Hs[2][2][MROW][LDH];   // [buf][dir][m][k]
    __shared__ __align__(16) short xscr[8][MROW][LDH];    // per-wave x scratch
    __shared__ __align__(16) short x2scr[2][MROW][LDH];   // waves 0,1: lk(x)

    const int tid  = threadIdx.x;
    const int wave = tid >> 6;
    const int lane = tid & 63;
    const int n    = lane & 15;   // batch row within tile
    const int quad = lane >> 4;
    const int row0 = blockIdx.x * MROW;

    const int dir  = wave >> 2;          // 0 fwd, 1 bwd
    const int cb   = wave & 3;           // 16-col block of hidden state
    const int jrow = cb * 16 + n;
    const int jq   = cb * 16 + quad * 4;
    const float* Wih = dir ? Wihb : Wihf;
    const float* Whh = dir ? Whhb : Whhf;
    const float* bih = dir ? bihb : bihf;
    const float* bhh = dir ? bhhb : bhhf;

    // ---- gate weight fragments (12) ----
    s16x8 wir0 = bfragW(Wih, NH,   0 + jrow, 0, quad);
    s16x8 wir1 = bfragW(Wih, NH,   0 + jrow, 1, quad);
    s16x8 wiz0 = bfragW(Wih, NH,  64 + jrow, 0, quad);
    s16x8 wiz1 = bfragW(Wih, NH,  64 + jrow, 1, quad);
    s16x8 win0 = bfragW(Wih, NH, 128 + jrow, 0, quad);
    s16x8 win1 = bfragW(Wih, NH, 128 + jrow, 1, quad);
    s16x8 whr0 = bfragW(Whh, NH,   0 + jrow, 0, quad);
    s16x8 whr1 = bfragW(Whh, NH,   0 + jrow, 1, quad);
    s16x8 whz0 = bfragW(Whh, NH,  64 + jrow, 0, quad);
    s16x8 whz1 = bfragW(Whh, NH,  64 + jrow, 1, quad);
    s16x8 whn0 = bfragW(Whh, NH, 128 + jrow, 0, quad);
    s16x8 whn1 = bfragW(Whh, NH, 128 + jrow, 1, quad);
    f32x4 initR, initZ;
    {
        f32x4 a = bias4(&bih[jq]),      b = bias4(&bhh[jq]);
        initR = a + b;
        f32x4 c = bias4(&bih[64 + jq]), d = bias4(&bhh[64 + jq]);
        initZ = c + d;
    }
    const f32x4 initN1 = bias4(&bih[128 + jq]);
    const f32x4 initN2 = bias4(&bhh[128 + jq]);

    // ---- full latent weight set (16 frags) — every wave, redundant ----
    s16x8 wl00 = bfragW(Wlat, 2 * NH,  0 + n, 0, quad);
    s16x8 wl01 = bfragW(Wlat, 2 * NH,  0 + n, 1, quad);
    s16x8 wl02 = bfragW(Wlat, 2 * NH,  0 + n, 2, quad);
    s16x8 wl03 = bfragW(Wlat, 2 * NH,  0 + n, 3, quad);
    s16x8 wl10 = bfragW(Wlat, 2 * NH, 16 + n, 0, quad);
    s16x8 wl11 = bfragW(Wlat, 2 * NH, 16 + n, 1, quad);
    s16x8 wl12 = bfragW(Wlat, 2 * NH, 16 + n, 2, quad);
    s16x8 wl13 = bfragW(Wlat, 2 * NH, 16 + n, 3, quad);
    s16x8 wl20 = bfragW(Wlat, 2 * NH, 32 + n, 0, quad);
    s16x8 wl21 = bfragW(Wlat, 2 * NH, 32 + n, 1, quad);
    s16x8 wl22 = bfragW(Wlat, 2 * NH, 32 + n, 2, quad);
    s16x8 wl23 = bfragW(Wlat, 2 * NH, 32 + n, 3, quad);
    s16x8 wl30 = bfragW(Wlat, 2 * NH, 48 + n, 0, quad);
    s16x8 wl31 = bfragW(Wlat, 2 * NH, 48 + n, 1, quad);
    s16x8 wl32 = bfragW(Wlat, 2 * NH, 48 + n, 2, quad);
    s16x8 wl33 = bfragW(Wlat, 2 * NH, 48 + n, 3, quad);
    const f32x4 bL0 = bias4(&blat[ 0 + quad * 4]);
    const f32x4 bL1 = bias4(&blat[16 + quad * 4]);
    const f32x4 bL2 = bias4(&blat[32 + quad * 4]);
    const f32x4 bL3 = bias4(&blat[48 + quad * 4]);

    // ---- out-proj (waves 0,1; loads safe for all) ----
    const int f0 = (wave & 1) * 16;
    s16x8 wo0 = bfragW(Wout, NH, f0 + n, 0, quad);
    s16x8 wo1 = bfragW(Wout, NH, f0 + n, 1, quad);
    const f32x4 initO = bias4(&bout[f0 + quad * 4]);
    float* const orow = out + (size_t)(row0 + n) * (NS * NF) + f0 + quad * 4;

    const f32x4 Z4 = {0.f, 0.f, 0.f, 0.f};

    // ---- prologue: h(1) = G(x0=0, h0=noise) -> Hs[0] ----
    f32x4 hreg;
    {
        const float4 nz = *(const float4*)&noise[(size_t)(row0 + n) * NH + jq];
        hreg[0] = nz.x; hreg[1] = nz.y; hreg[2] = nz.z; hreg[3] = nz.w;
        s16x8 nf0 = bfragW(noise, NH, row0 + n, 0, quad);
        s16x8 nf1 = bfragW(noise, NH, row0 + n, 1, quad);
        f32x4 aR  = MFMA(whr0, nf0, initR);  aR  = MFMA(whr1, nf1, aR);
        f32x4 aZ  = MFMA(whz0, nf0, initZ);  aZ  = MFMA(whz1, nf1, aZ);
        f32x4 aN2 = MFMA(whn0, nf0, initN2); aN2 = MFMA(whn1, nf1, aN2);
        hreg = gru_up(aR, aZ, initN1, aN2, hreg);   // gi = 0 (x0 = 0)
        *(int2*)&Hs[0][dir][n][jq] = pk4bf(hreg);
    }
    __syncthreads();

#define WINDOW(HB, T) do {                                                      \
    /* h(T+1), both directions */                                               \
    s16x8 fa0 = *(const s16x8*)&Hs[HB][0][n][quad * 8];                         \
    s16x8 fa1 = *(const s16x8*)&Hs[HB][0][n][32 + quad * 8];                    \
    s16x8 ba0 = *(const s16x8*)&Hs[HB][1][n][quad * 8];                         \
    s16x8 ba1 = *(const s16x8*)&Hs[HB][1][n][32 + quad * 8];                    \
    /* full latent, redundant per wave: x(T+1) = ys[T] in D-layout */           \
    f32x4 c1, c2, la0, la1, la2, la3;                                           \
    c1 = MFMA(wl00, fa0, bL0); c1 = MFMA(wl01, fa1, c1);                        \
    c2 = MFMA(wl02, ba0, Z4);  c2 = MFMA(wl03, ba1, c2);                        \
    la0 = v_lk(c1 + c2);                                                        \
    c1 = MFMA(wl10, fa0, bL1); c1 = MFMA(wl11, fa1, c1);                        \
    c2 = MFMA(wl12, ba0, Z4);  c2 = MFMA(wl13, ba1, c2);                        \
    la1 = v_lk(c1 + c2);                                                        \
    c1 = MFMA(wl20, fa0, bL2); c1 = MFMA(wl21, fa1, c1);                        \
    c2 = MFMA(wl22, ba0, Z4);  c2 = MFMA(wl23, ba1, c2);                        \
    la2 = v_lk(c1 + c2);                                                        \
    c1 = MFMA(wl30, fa0, bL3); c1 = MFMA(wl31, fa1, c1);                        \
    c2 = MFMA(wl32, ba0, Z4);  c2 = MFMA(wl33, ba1, c2);                        \
    la3 = v_lk(c1 + c2);                                                        \
    /* wave-local D->A layout fix through own scratch (no barrier) */           \
    *(int2*)&xscr[wave][n][ 0 + quad * 4] = pk4bf(la0);                         \
    *(int2*)&xscr[wave][n][16 + quad * 4] = pk4bf(la1);                         \
    *(int2*)&xscr[wave][n][32 + quad * 4] = pk4bf(la2);                         \
    *(int2*)&xscr[wave][n][48 + quad * 4] = pk4bf(la3);                         \
    if (wave < 2) {                                                             \
        *(int2*)&x2scr[wave][n][ 0 + quad * 4] = pk4bf(v_lk(la0));              \
        *(int2*)&x2scr[wave][n][16 + quad * 4] = pk4bf(v_lk(la1));              \
        *(int2*)&x2scr[wave][n][32 + quad * 4] = pk4bf(v_lk(la2));              \
        *(int2*)&x2scr[wave][n][48 + quad * 4] = pk4bf(v_lk(la3));              \
    }                                                                           \
    s16x8 xa0 = *(const s16x8*)&xscr[wave][n][quad * 8];                        \
    s16x8 xa1 = *(const s16x8*)&xscr[wave][n][32 + quad * 8];                   \
    /* out-proj + y(T) store, waves 0,1 (no pipeline delay) */                  \
    if (wave < 2) {                                                             \
        s16x8 p0 = *(const s16x8*)&x2scr[wave][n][quad * 8];                    \
        s16x8 p1 = *(const s16x8*)&x2scr[wave][n][32 + quad * 8];               \
        f32x4 po = MFMA(wo0, p0, initO);                                        \
        po = MFMA(wo1, p1, po);                                                 \
        *(f32x4*)(orow + (size_t)(T) * NF) = v_sigm(po);                        \
    }                                                                           \
    /* gates: h(T+2) = G(x(T+1), h(T+1)) */                                     \
    s16x8 ha0 = dir ? ba0 : fa0;                                                \
    s16x8 ha1 = dir ? ba1 : fa1;                                                \
    f32x4 gR = MFMA(wir0, xa0, initR);  gR = MFMA(wir1, xa1, gR);               \
    f32x4 hR = MFMA(whr0, ha0, Z4);     hR = MFMA(whr1, ha1, hR);               \
    f32x4 gZ = MFMA(wiz0, xa0, initZ);  gZ = MFMA(wiz1, xa1, gZ);               \
    f32x4 hZ = MFMA(whz0, ha0, Z4);     hZ = MFMA(whz1, ha1, hZ);               \
    f32x4 aN1 = MFMA(win0, xa0, initN1); aN1 = MFMA(win1, xa1, aN1);            \
    f32x4 aN2 = MFMA(whn0, ha0, initN2); aN2 = MFMA(whn1, ha1, aN2);            \
    hreg = gru_up(gR + hR, gZ + hZ, aN1, aN2, hreg);                            \
    *(int2*)&Hs[(HB) ^ 1][dir][n][jq] = pk4bf(hreg);                            \
    __syncthreads();                                                            \
} while (0)

    for (int t = 0; t < NS; t += 2) {
        WINDOW(0, t);
        WINDOW(1, t + 1);
    }
#undef WINDOW
    // last window stores y(NS-1) and computes h(NS+1) harmlessly — no epilogue
}

extern "C" void kernel_launch(void* const* d_in, const int* in_sizes, int n_in,
                              void* d_out, int out_size, void* d_ws, size_t ws_size,
                              hipStream_t stream) {
    const float* noise = (const float*)d_in[0];
    const float* Wihf  = (const float*)d_in[1];
    const float* Whhf  = (const float*)d_in[2];
    const float* bihf  = (const float*)d_in[3];
    const float* bhhf  = (const float*)d_in[4];
    const float* Wihb  = (const float*)d_in[5];
    const float* Whhb  = (const float*)d_in[6];
    const float* bihb  = (const float*)d_in[7];
    const float* bhhb  = (const float*)d_in[8];
    const float* Wlat  = (const float*)d_in[9];
    const float* blat  = (const float*)d_in[10];
    const float* Wout  = (const float*)d_in[11];
    const float* bout  = (const float*)d_in[12];

    grugan_kernel<<<dim3(NBATCH / MROW), dim3(512), 0, stream>>>(
        noise, Wihf, Whhf, bihf, bhhf, Wihb, Whhb, bihb, bhhb,
        Wlat, blat, Wout, bout, (float*)d_out);
}

// Round 11
// 1620.861 us; speedup vs baseline: 1.5472x; 1.5472x over previous
//
#include <hip/hip_runtime.h>
#include <hip/hip_bf16.h>

// GRU-GAN generator, MI355X. Round 11 — R9 specialization + register pinning.
// B=512, H=64, S=2048, F=32. 32 blocks x 1024 threads (16 waves, 4/EU).
// Block = 16 batch rows (M=16 MFMA tile, transposed D[j][m] layout).
//   waves 0-7 : gates (dir=w>>2, cb=w&3). W1: x-read, 6 gi MFMA, merged-rcp
//               GRU elementwise, packed h write. W2: 6 gh MFMA (carried regs).
//   waves 8-11: latent, W2 only: h(t+1) read (both dirs), 2x2-chain MFMA,
//               leaky, packed Xs/X2s writes.
//   waves 12-13: out-proj, W1 only (input X2s was published at prev b2):
//               read, 2 MFMA, sigm, direct y store.
//   waves 14-15: barrier-matched idle.
// R11 fixes vs R9 (which flatlined because the RA REMATERIALIZED loop-invariant
// fragments/biases from global inside the t-loop — R9: VGPR_Count=64 (too small
// for 12 frags+biases), FETCH 1368 MB vs 1070 baseline; R10 worse: 2850 MB):
//  * asm("" : "+v"(x)) pins every loop-invariant fragment/bias — opaque to the
//    RA, cannot be rematerialized from global. waves_per_eu(4,4) -> 128 budget.
//  * custom barrier: s_waitcnt lgkmcnt(0) + s_barrier (no vmcnt(0) drain).
//  * latent MFMA restructured 4-chain -> two 2-chains + add.
// Exactly 2 barriers/step on every path.

#define NBATCH 512
#define NH 64
#define NS 2048
#define NF 32
#define MROW 16
#define LDH 72    // padded LDS row stride (shorts): 144 B

typedef short s16x8 __attribute__((ext_vector_type(8)));
typedef float f32x4 __attribute__((ext_vector_type(4)));

#define MFMA(a, b, c) __builtin_amdgcn_mfma_f32_16x16x32_bf16((a), (b), (c), 0, 0, 0)

#define NLOG2E  (-1.4426950408889634f)
#define N2LOG2E (-2.8853900817779268f)

// pin a value in VGPRs: opaque to rematerialization
#define PIN(x) __asm__("" : "+v"(x))

// barrier that waits only on LDS (no vmcnt drain like __syncthreads)
__device__ __forceinline__ void bar_lds() {
    __asm__ volatile("s_waitcnt lgkmcnt(0)\n\ts_barrier" ::: "memory");
}

__device__ __forceinline__ short f2bf(float f) {
    return (short)((__float_as_uint(f) + 0x8000u) >> 16);
}

__device__ __forceinline__ f32x4 v_exp2(f32x4 a) {
    f32x4 r;
#pragma unroll
    for (int i = 0; i < 4; ++i) r[i] = __builtin_amdgcn_exp2f(a[i]);
    return r;
}

__device__ __forceinline__ f32x4 v_rcp(f32x4 a) {
    f32x4 r;
#pragma unroll
    for (int i = 0; i < 4; ++i) r[i] = __builtin_amdgcn_rcpf(a[i]);
    return r;
}

__device__ __forceinline__ f32x4 v_lk(f32x4 a) {
    f32x4 b = a * 0.01f;
    f32x4 r;
#pragma unroll
    for (int i = 0; i < 4; ++i) r[i] = fmaxf(a[i], b[i]);
    return r;
}

__device__ __forceinline__ f32x4 v_sigm(f32x4 a) {
    return v_rcp(v_exp2(a * NLOG2E) + 1.0f);
}

__device__ __forceinline__ int2 pk4bf(f32x4 v) {
    union { __hip_bfloat162 b; int i; } lo, hi;
    float2 a; a.x = v[0]; a.y = v[1];
    float2 b; b.x = v[2]; b.y = v[3];
    lo.b = __float22bfloat162_rn(a);
    hi.b = __float22bfloat162_rn(b);
    int2 r; r.x = lo.i; r.y = hi.i;
    return r;
}

__device__ __forceinline__ s16x8 bfragW(const float* __restrict__ W, int ldk,
                                        int row, int kf, int quad) {
    const float* p = W + (size_t)row * ldk + kf * 32 + quad * 8;
    s16x8 r;
#pragma unroll
    for (int i = 0; i < 8; ++i) r[i] = f2bf(p[i]);
    return r;
}

__device__ __forceinline__ f32x4 bias4(const float* __restrict__ p) {
    const float4 v = *(const float4*)p;
    f32x4 r = {v.x, v.y, v.z, v.w};
    return r;
}

__global__ __launch_bounds__(1024)
__attribute__((amdgpu_waves_per_eu(4, 4)))
void grugan_kernel(const float* __restrict__ noise,
                   const float* __restrict__ Wihf, const float* __restrict__ Whhf,
                   const float* __restrict__ bihf, const float* __restrict__ bhhf,
                   const float* __restrict__ Wihb, const float* __restrict__ Whhb,
                   const float* __restrict__ bihb, const float* __restrict__ bhhb,
                   const float* __restrict__ Wlat, const float* __restrict__ blat,
                   const float* __restrict__ Wout, const float* __restrict__ bout,
                   float* __restrict__ out)
{
    __shared__ __align__(16) short Xs[2][MROW][LDH];
    __shared__ __align__(16) short X2s[2][MROW][LDH];
    __shared__ __align__(16) short Hs[2][2][MROW][LDH];

    const int tid  = threadIdx.x;
    const int wave = tid >> 6;
    const int lane = tid & 63;
    const int n    = lane & 15;   // batch row within tile
    const int quad = lane >> 4;
    const int row0 = blockIdx.x * MROW;

    // zero x(0); init h(0) (gate waves hold hreg; both dirs covered)
    for (int idx = tid; idx < MROW * LDH; idx += 1024) (&Xs[0][0][0])[idx] = 0;
    f32x4 hreg = {0.f, 0.f, 0.f, 0.f};
    const int gdir = wave >> 2;             // valid for waves 0-7
    const int gjq  = (wave & 3) * 16 + quad * 4;
    if (wave < 8) {
        const float4 nz = *(const float4*)&noise[(size_t)(row0 + n) * NH + gjq];
        hreg[0] = nz.x; hreg[1] = nz.y; hreg[2] = nz.z; hreg[3] = nz.w;
        *(int2*)&Hs[0][gdir][n][gjq] = pk4bf(hreg);
    }
    __syncthreads();

    if (wave < 8) {
        // ======================= GATE WAVES =======================
        const int dir  = gdir;
        const int cb   = wave & 3;
        const int jrow = cb * 16 + n;
        const int jq   = gjq;
        const float* Wih = dir ? Wihb : Wihf;
        const float* Whh = dir ? Whhb : Whhf;
        const float* bih = dir ? bihb : bihf;
        const float* bhh = dir ? bhhb : bhhf;

        s16x8 wir0 = bfragW(Wih, NH,   0 + jrow, 0, quad);
        s16x8 wir1 = bfragW(Wih, NH,   0 + jrow, 1, quad);
        s16x8 wiz0 = bfragW(Wih, NH,  64 + jrow, 0, quad);
        s16x8 wiz1 = bfragW(Wih, NH,  64 + jrow, 1, quad);
        s16x8 win0 = bfragW(Wih, NH, 128 + jrow, 0, quad);
        s16x8 win1 = bfragW(Wih, NH, 128 + jrow, 1, quad);
        s16x8 whr0 = bfragW(Whh, NH,   0 + jrow, 0, quad);
        s16x8 whr1 = bfragW(Whh, NH,   0 + jrow, 1, quad);
        s16x8 whz0 = bfragW(Whh, NH,  64 + jrow, 0, quad);
        s16x8 whz1 = bfragW(Whh, NH,  64 + jrow, 1, quad);
        s16x8 whn0 = bfragW(Whh, NH, 128 + jrow, 0, quad);
        s16x8 whn1 = bfragW(Whh, NH, 128 + jrow, 1, quad);
        f32x4 initR, initZ;
        {
            f32x4 a = bias4(&bih[jq]),      b = bias4(&bhh[jq]);
            initR = a + b;
            f32x4 c = bias4(&bih[64 + jq]), d = bias4(&bhh[64 + jq]);
            initZ = c + d;
        }
        f32x4 initN1 = bias4(&bih[128 + jq]);
        f32x4 initN2 = bias4(&bhh[128 + jq]);
        // pin all loop-invariants: RA must keep them resident (no remat)
        PIN(wir0); PIN(wir1); PIN(wiz0); PIN(wiz1); PIN(win0); PIN(win1);
        PIN(whr0); PIN(whr1); PIN(whz0); PIN(whz1); PIN(whn0); PIN(whn1);
        PIN(initR); PIN(initZ); PIN(initN1); PIN(initN2);

        // prologue: gh accumulators for t=0 from h(0)
        f32x4 accR, accZ, accN2;
        {
            s16x8 ha0 = *(const s16x8*)&Hs[0][dir][n][quad * 8];
            s16x8 ha1 = *(const s16x8*)&Hs[0][dir][n][32 + quad * 8];
            accR  = MFMA(whr0, ha0, initR);  accR  = MFMA(whr1, ha1, accR);
            accZ  = MFMA(whz0, ha0, initZ);  accZ  = MFMA(whz1, ha1, accZ);
            accN2 = MFMA(whn0, ha0, initN2); accN2 = MFMA(whn1, ha1, accN2);
        }

#define GSTEP(HB) do {                                                          \
        s16x8 xa0 = *(const s16x8*)&Xs[HB][n][quad * 8];                        \
        s16x8 xa1 = *(const s16x8*)&Xs[HB][n][32 + quad * 8];                   \
        accR = MFMA(wir0, xa0, accR);   accR = MFMA(wir1, xa1, accR);           \
        accZ = MFMA(wiz0, xa0, accZ);   accZ = MFMA(wiz1, xa1, accZ);           \
        f32x4 accN1 = MFMA(win0, xa0, initN1);                                  \
        accN1 = MFMA(win1, xa1, accN1);                                         \
        f32x4 eR = v_exp2(accR * NLOG2E);                                       \
        f32x4 rr = v_rcp(eR + 1.0f);                                            \
        f32x4 u  = accN1 + rr * accN2;                                          \
        f32x4 eU = v_exp2(u * N2LOG2E);                                         \
        f32x4 eZ = v_exp2(accZ * NLOG2E);                                       \
        f32x4 numer = (eZ + hreg) + eU * (hreg - eZ);                           \
        f32x4 denom = (eU + 1.0f) * (eZ + 1.0f);                                \
        hreg = numer * v_rcp(denom);                                            \
        *(int2*)&Hs[(HB) ^ 1][dir][n][jq] = pk4bf(hreg);                        \
        bar_lds();  /* b1: H(t+1) visible */                                    \
        {                                                                       \
            s16x8 ha0 = *(const s16x8*)&Hs[(HB) ^ 1][dir][n][quad * 8];         \
            s16x8 ha1 = *(const s16x8*)&Hs[(HB) ^ 1][dir][n][32 + quad * 8];    \
            accR  = MFMA(whr0, ha0, initR);  accR  = MFMA(whr1, ha1, accR);     \
            accZ  = MFMA(whz0, ha0, initZ);  accZ  = MFMA(whz1, ha1, accZ);     \
            accN2 = MFMA(whn0, ha0, initN2); accN2 = MFMA(whn1, ha1, accN2);    \
        }                                                                       \
        bar_lds();  /* b2: x(t+1) visible */                                    \
    } while (0)

        for (int t = 0; t < NS; t += 2) {
            GSTEP(0);
            GSTEP(1);
        }
#undef GSTEP
    } else if (wave < 12) {
        // ======================= LATENT WAVES =======================
        const int lt = wave & 3;
        const int nq = lt * 16 + quad * 4;
        s16x8 wl0 = bfragW(Wlat, 2 * NH, lt * 16 + n, 0, quad);
        s16x8 wl1 = bfragW(Wlat, 2 * NH, lt * 16 + n, 1, quad);
        s16x8 wl2 = bfragW(Wlat, 2 * NH, lt * 16 + n, 2, quad);
        s16x8 wl3 = bfragW(Wlat, 2 * NH, lt * 16 + n, 3, quad);
        f32x4 initL = bias4(&blat[lt * 16 + quad * 4]);
        PIN(wl0); PIN(wl1); PIN(wl2); PIN(wl3); PIN(initL);
        const f32x4 Z4 = {0.f, 0.f, 0.f, 0.f};

#define LSTEP(HB) do {                                                          \
        bar_lds();  /* b1: H(t+1) visible */                                    \
        s16x8 fa0 = *(const s16x8*)&Hs[(HB) ^ 1][0][n][quad * 8];               \
        s16x8 fa1 = *(const s16x8*)&Hs[(HB) ^ 1][0][n][32 + quad * 8];          \
        s16x8 ba0 = *(const s16x8*)&Hs[(HB) ^ 1][1][n][quad * 8];               \
        s16x8 ba1 = *(const s16x8*)&Hs[(HB) ^ 1][1][n][32 + quad * 8];          \
        f32x4 c1 = MFMA(wl0, fa0, initL);                                       \
        c1 = MFMA(wl1, fa1, c1);                                                \
        f32x4 c2 = MFMA(wl2, ba0, Z4);                                          \
        c2 = MFMA(wl3, ba1, c2);                                                \
        f32x4 la = v_lk(c1 + c2);                                               \
        *(int2*)&Xs[(HB) ^ 1][n][nq]  = pk4bf(la);                              \
        *(int2*)&X2s[(HB) ^ 1][n][nq] = pk4bf(v_lk(la));                        \
        bar_lds();  /* b2: x(t+1) visible */                                    \
    } while (0)

        for (int t = 0; t < NS; t += 2) {
            LSTEP(0);
            LSTEP(1);
        }
#undef LSTEP
    } else if (wave < 14) {
        // ===== OUT-PROJ WAVES (work in W1; X2s[HB] published at prev b2) =====
        const int f0 = (wave & 1) * 16;
        s16x8 wo0 = bfragW(Wout, NH, f0 + n, 0, quad);
        s16x8 wo1 = bfragW(Wout, NH, f0 + n, 1, quad);
        f32x4 initO = bias4(&bout[f0 + quad * 4]);
        PIN(wo0); PIN(wo1); PIN(initO);
        float* const orow = out + (size_t)(row0 + n) * (NS * NF) + f0 + quad * 4;

#define OSTEP(HB, T) do {                                                       \
        if ((T) >= 1) {                                                         \
            s16x8 p0 = *(const s16x8*)&X2s[HB][n][quad * 8];                    \
            s16x8 p1 = *(const s16x8*)&X2s[HB][n][32 + quad * 8];               \
            f32x4 po = MFMA(wo0, p0, initO);                                    \
            po = MFMA(wo1, p1, po);                                             \
            *(f32x4*)(orow + (size_t)((T) - 1) * NF) = v_sigm(po);              \
        }                                                                       \
        bar_lds();  /* b1 */                                                    \
        bar_lds();  /* b2 */                                                    \
    } while (0)

        for (int t = 0; t < NS; t += 2) {
            OSTEP(0, t);
            OSTEP(1, t + 1);
        }
#undef OSTEP

        // epilogue: y(NS-1) from X2s[0] (= lk(x(NS)), written at t=NS-1's W2)
        s16x8 p0 = *(const s16x8*)&X2s[0][n][quad * 8];
        s16x8 p1 = *(const s16x8*)&X2s[0][n][32 + quad * 8];
        f32x4 po = MFMA(wo0, p0, initO);
        po = MFMA(wo1, p1, po);
        *(f32x4*)(orow + (size_t)(NS - 1) * NF) = v_sigm(po);
    } else {
        // ======================= IDLE WAVES (barrier-matched) ==========
#pragma unroll 1
        for (int i = 0; i < 2 * NS; ++i) bar_lds();
    }
}

extern "C" void kernel_launch(void* const* d_in, const int* in_sizes, int n_in,
                              void* d_out, int out_size, void* d_ws, size_t ws_size,
                              hipStream_t stream) {
    const float* noise = (const float*)d_in[0];
    const float* Wihf  = (const float*)d_in[1];
    const float* Whhf  = (const float*)d_in[2];
    const float* bihf  = (const float*)d_in[3];
    const float* bhhf  = (const float*)d_in[4];
    const float* Wihb  = (const float*)d_in[5];
    const float* Whhb  = (const float*)d_in[6];
    const float* bihb  = (const float*)d_in[7];
    const float* bhhb  = (const float*)d_in[8];
    const float* Wlat  = (const float*)d_in[9];
    const float* blat  = (const float*)d_in[10];
    const float* Wout  = (const float*)d_in[11];
    const float* bout  = (const float*)d_in[12];

    grugan_kernel<<<dim3(NBATCH / MROW), dim3(1024), 0, stream>>>(
        noise, Wihf, Whhf, bihf, bhhf, Wihb, Whhb, bihb, bhhb,
        Wlat, blat, Wout, bout, (float*)d_out);
}